// Round 11
// baseline (146.545 us; speedup 1.0000x reference)
//
#include <hip/hip_runtime.h>
#include <math.h>

// TSC (order-3) particle-to-mesh deposition.
//
// Fast path (C==8, n%4==0, n<=256): per-1x1-column capped bin lists of
// PACKED 48B records, then WAVE-SCATTER-GATHER: one wave per (x,y) column,
// lanes = (atom-slot, z-corner) pairs, 8 ds_add_f32 into the wave's PRIVATE
// LDS column [8ch][n], then per-channel float4 streaming writeout.
// r11 changes vs r10 (which plateaued at ~145us, ~1.85 TB/s write):
//  (1) NO block barrier -- each wave's LDS column is private, so waves
//      write out independently (r10 coupled 4 waves to the slowest's
//      Poisson tail and synchronized store bursts);
//  (2) PLAIN stores (not nontemporal) -- let L2 aggregate writes like the
//      6.6 TB/s harness fill does, instead of bypassing to HBM;
//  (3) bijective XCD swizzle of block->column map so each XCD's L2 owns a
//      contiguous 32MB x-slab of the output (default round-robin shreds
//      adjacent columns across 8 L2s -> strided HBM write streams).
//
// Fallbacks: interleaved-atomic two-phase (C==8), generic planar atomics.

#define KColCAP 16   // records per 1x1 column bin (lambda ~2.5)

typedef float nfloat4 __attribute__((ext_vector_type(4)));

// TSC weight for axis offset o in {-1,0,+1} at fractional distance d in [-0.5,0.5]
__device__ __forceinline__ float tsc_w(int o, float d) {
    float t = 0.5f + (float)o * d;
    return (o == 0) ? (0.75f - d * d) : (0.5f * t * t);
}

__device__ __forceinline__ float inv_spacing(const float* __restrict__ cell, int n) {
    float tr = cell[0] + cell[4] + cell[8];
    return (3.0f * (float)n) / tr;
}

// ---------------- binning: packed records into 1x1-column lists ----------------

__global__ __launch_bounds__(256) void fill_recs(
    const float* __restrict__ pos, const float* __restrict__ cell,
    const float* __restrict__ emb,
    int* __restrict__ counts, int* __restrict__ ovf_cnt,
    float4* __restrict__ binrec, int* __restrict__ ovf,
    int N, int n)
{
    int i = blockIdx.x * blockDim.x + threadIdx.x;
    if (i >= N) return;
    float inv_sp = inv_spacing(cell, n);
    float px = pos[3 * i + 0] * inv_sp;
    float py = pos[3 * i + 1] * inv_sp;
    float pz = pos[3 * i + 2] * inv_sp;
    int cx = (int)rintf(px); if (cx >= n) cx -= n; else if (cx < 0) cx += n;
    int cy = (int)rintf(py); if (cy >= n) cy -= n; else if (cy < 0) cy += n;
    int bin = cx * n + cy;
    int slot = atomicAdd(&counts[bin], 1);
    if (slot < KColCAP) {
        const float4* e4 = (const float4*)(emb + (size_t)i * 8);
        float4* r = binrec + (size_t)(bin * KColCAP + slot) * 3;
        r[0] = make_float4(px, py, pz, 0.0f);
        r[1] = e4[0];
        r[2] = e4[1];
    } else {
        int o = atomicAdd(ovf_cnt, 1);
        ovf[o] = i;   // ovf sized N: cannot overflow
    }
}

// ---------------- wave-scatter gather: one wave per column ----------------
// 1D grid of nb = (n/4)*n blocks; bijective XCD swizzle maps block -> (x,ygrp)
// so each XCD gets a contiguous x-slab. Wave wv handles column (x, ygrp*4+wv);
// LDS: per-wave private column [8ch][n]. No block barrier.

__global__ __launch_bounds__(256) void gather_scatter(
    const float4* __restrict__ binrec, const int* __restrict__ counts,
    float* __restrict__ out, int n, int nzc)
{
    extern __shared__ float lds[];
    const int tid = threadIdx.x;
    const int lane = tid & 63;
    const int wv = tid >> 6;

    // bijective XCD swizzle (m204): XCD c owns a contiguous sb-range
    const int nb = nzc * n;
    const int b = blockIdx.x;
    const int q = nb >> 3, r = nb & 7;
    const int xcd = b & 7, idx = b >> 3;
    const int sb = (xcd < r) ? (xcd * (q + 1) + idx)
                             : (r * (q + 1) + (xcd - r) * q + idx);
    const int x = sb / nzc;
    const int ygrp = sb - x * nzc;
    const int y = ygrp * 4 + wv;

    float* col = lds + wv * 8 * n;     // [8][n] private to this wave

    // zero this wave's column (8n floats = 2n float4)
    {
        nfloat4* c4 = (nfloat4*)col;
        const int z4 = 2 * n;
        for (int i = lane; i < z4; i += 64)
            c4[i] = (nfloat4)(0.f);
    }

    // 9 neighbor-bin meta in registers (wave-uniform broadcast loads)
    int base[9], pref[10];
    pref[0] = 0;
    #pragma unroll
    for (int j = 0; j < 9; ++j) {
        int jx = j / 3, jy = j - 3 * (j / 3);       // compile-time per j
        int xb = x + jx - 1; if (xb < 0) xb += n; else if (xb >= n) xb -= n;
        int yb = y + jy - 1; if (yb < 0) yb += n; else if (yb >= n) yb -= n;
        int bin = xb * n + yb;
        base[j] = bin * KColCAP;
        int c = counts[bin];
        c = (c < KColCAP) ? c : KColCAP;
        pref[j + 1] = pref[j] + c;
    }
    const int tot = pref[9];

    // lane = (atom slot s, z-corner zc)
    const int s  = lane / 3;           // 0..21 (lane 63 -> s=21, inactive)
    const int zc = lane - 3 * s - 1;   // -1, 0, +1

    for (int q0 = 0; q0 < tot; q0 += 21) {
        const int qq = q0 + s;
        if (s < 21 && qq < tot) {
            // select bin j and record index via unrolled cndmask chain
            int rec = base[0] + qq;
            int jxv = 0, jyv = 0;
            #pragma unroll
            for (int k = 1; k < 9; ++k) {
                bool ge = (qq >= pref[k]);
                int cand = base[k] + (qq - pref[k]);
                rec = ge ? cand : rec;
                jxv = ge ? (k / 3) : jxv;            // constants: k/3, k%3
                jyv = ge ? (k - 3 * (k / 3)) : jyv;
            }
            const float4* rp = binrec + (size_t)rec * 3;
            float4 P  = rp[0];
            float4 e0 = rp[1];
            float4 e1 = rp[2];

            float cxf = rintf(P.x); float dx = P.x - cxf;
            float cyf = rintf(P.y); float dy = P.y - cyf;
            float czf = rintf(P.z); float dz = P.z - czf;

            // xy corner weight: cell offset o = 1 - j (exact by bin construction)
            float tx = 0.5f + (float)(1 - jxv) * dx;
            float wx = (jxv == 1) ? (0.75f - dx * dx) : (0.5f * tx * tx);
            float ty = 0.5f + (float)(1 - jyv) * dy;
            float wy = (jyv == 1) ? (0.75f - dy * dy) : (0.5f * ty * ty);
            float tz = 0.5f + (float)zc * dz;
            float wz = (zc == 0) ? (0.75f - dz * dz) : (0.5f * tz * tz);
            float w = wx * wy * wz;

            int cz = (int)czf; if (cz >= n) cz -= n; else if (cz < 0) cz += n;
            int z = cz + zc; if (z < 0) z += n; else if (z >= n) z -= n;

            float* p = col + z;                       // ch stride n (imm offset)
            atomicAdd(p + 0 * n, w * e0.x);
            atomicAdd(p + 1 * n, w * e0.y);
            atomicAdd(p + 2 * n, w * e0.z);
            atomicAdd(p + 3 * n, w * e0.w);
            atomicAdd(p + 4 * n, w * e1.x);
            atomicAdd(p + 5 * n, w * e1.y);
            atomicAdd(p + 6 * n, w * e1.z);
            atomicAdd(p + 7 * n, w * e1.w);
        }
    }
    // NO __syncthreads(): column is wave-private; compiler orders the
    // following ds_reads after the atomics via lgkmcnt.

    // writeout: per channel one PLAIN float4 per lane (z = 4*lane..+3);
    // plain stores allocate in L2 -> L2 aggregates and streams to HBM.
    const int z0 = lane * 4;
    if (z0 < n) {
        const size_t n3 = (size_t)n * n * n;
        const size_t colbase = ((size_t)x * n + y) * (size_t)n + z0;
        #pragma unroll
        for (int ch = 0; ch < 8; ++ch) {
            nfloat4 v = *(const nfloat4*)(col + ch * n + z0);
            *(nfloat4*)(out + (size_t)ch * n3 + colbase) = v;
        }
    }
}

// overflow cleanup: global planar atomics for atoms that missed their bin list
__global__ __launch_bounds__(256) void deposit_overflow(
    const float* __restrict__ pos, const float* __restrict__ cell,
    const float* __restrict__ emb, const int* __restrict__ ovf_cnt,
    const int* __restrict__ ovf, float* __restrict__ out, int n)
{
    int m = *ovf_cnt;
    int i = blockIdx.x * blockDim.x + threadIdx.x;
    if (i >= m) return;
    int ai = ovf[i];
    float inv_sp = inv_spacing(cell, n);
    float p[3], d[3]; int c0[3];
    #pragma unroll
    for (int kk = 0; kk < 3; ++kk) {
        p[kk] = pos[3 * ai + kk] * inv_sp;
        c0[kk] = (int)rintf(p[kk]);
        d[kk] = p[kk] - (float)c0[kk];
    }
    float w[3][3];
    #pragma unroll
    for (int kk = 0; kk < 3; ++kk) {
        float dd = d[kk];
        w[kk][0] = tsc_w(-1, dd); w[kk][1] = tsc_w(0, dd); w[kk][2] = tsc_w(1, dd);
    }
    int W[3][3];
    #pragma unroll
    for (int kk = 0; kk < 3; ++kk)
        #pragma unroll
        for (int a = 0; a < 3; ++a) {
            int v = c0[kk] - 1 + a; if (v < 0) v += n; else if (v >= n) v -= n;
            W[kk][a] = v;
        }
    size_t n3 = (size_t)n * n * n;
    const float4* e4 = (const float4*)(emb + (size_t)ai * 8);
    float4 e0 = e4[0], e1 = e4[1];
    float e[8] = {e0.x, e0.y, e0.z, e0.w, e1.x, e1.y, e1.z, e1.w};
    for (int a = 0; a < 3; ++a)
        for (int bq = 0; bq < 3; ++bq)
            for (int cq = 0; cq < 3; ++cq) {
                float wt = w[0][a] * w[1][bq] * w[2][cq];
                size_t g = ((size_t)W[0][a] * n + W[1][bq]) * n + W[2][cq];
                #pragma unroll
                for (int ch = 0; ch < 8; ++ch)
                    atomicAdd(out + (size_t)ch * n3 + g, wt * e[ch]);
            }
}

// ---------------- fallback: interleaved atomics + transpose ----------------

__global__ __launch_bounds__(256) void deposit_tsc8_ilv(
    const float* __restrict__ pos,
    const float* __restrict__ cell,
    const float* __restrict__ emb,
    float* __restrict__ ws,
    int total, int n)
{
    int t = blockIdx.x * blockDim.x + threadIdx.x;
    if (t >= total) return;
    int atom = t / 27;
    int c    = t - atom * 27;
    int a    = c / 9;
    int rem  = c - a * 9;
    int b    = rem / 3;
    int cc   = rem - b * 3;

    float inv_sp = inv_spacing(cell, n);

    float px = pos[3 * atom + 0] * inv_sp;
    float py = pos[3 * atom + 1] * inv_sp;
    float pz = pos[3 * atom + 2] * inv_sp;

    int cx = (int)rintf(px);  float dx = px - (float)cx;
    int cy = (int)rintf(py);  float dy = py - (float)cy;
    int cz = (int)rintf(pz);  float dz = pz - (float)cz;

    float w = tsc_w(a - 1, dx) * tsc_w(b - 1, dy) * tsc_w(cc - 1, dz);

    int x = cx - 1 + a;  if (x < 0) x += n; else if (x >= n) x -= n;
    int y = cy - 1 + b;  if (y < 0) y += n; else if (y >= n) y -= n;
    int z = cz - 1 + cc; if (z < 0) z += n; else if (z >= n) z -= n;

    const float4* e4 = (const float4*)(emb + (size_t)atom * 8);
    float4 e0 = e4[0], e1 = e4[1];

    float* p = ws + ((size_t)((x * n + y) * n + z)) * 8;
    atomicAdd(p + 0, w * e0.x);
    atomicAdd(p + 1, w * e0.y);
    atomicAdd(p + 2, w * e0.z);
    atomicAdd(p + 3, w * e0.w);
    atomicAdd(p + 4, w * e1.x);
    atomicAdd(p + 5, w * e1.y);
    atomicAdd(p + 6, w * e1.z);
    atomicAdd(p + 7, w * e1.w);
}

__global__ __launch_bounds__(256) void transpose_ilv8(
    const float* __restrict__ ws, float* __restrict__ out, int n3)
{
    int t = blockIdx.x * blockDim.x + threadIdx.x;
    int g0 = t * 4;
    if (g0 >= n3) return;
    const float4* w4 = (const float4*)(ws + (size_t)g0 * 8);
    float4 r0 = w4[0], r1 = w4[1];
    float4 r2 = w4[2], r3 = w4[3];
    float4 r4 = w4[4], r5 = w4[5];
    float4 r6 = w4[6], r7 = w4[7];

    *(float4*)(out + (size_t)0 * n3 + g0) = make_float4(r0.x, r2.x, r4.x, r6.x);
    *(float4*)(out + (size_t)1 * n3 + g0) = make_float4(r0.y, r2.y, r4.y, r6.y);
    *(float4*)(out + (size_t)2 * n3 + g0) = make_float4(r0.z, r2.z, r4.z, r6.z);
    *(float4*)(out + (size_t)3 * n3 + g0) = make_float4(r0.w, r2.w, r4.w, r6.w);
    *(float4*)(out + (size_t)4 * n3 + g0) = make_float4(r1.x, r3.x, r5.x, r7.x);
    *(float4*)(out + (size_t)5 * n3 + g0) = make_float4(r1.y, r3.y, r5.y, r7.y);
    *(float4*)(out + (size_t)6 * n3 + g0) = make_float4(r1.z, r3.z, r5.z, r7.z);
    *(float4*)(out + (size_t)7 * n3 + g0) = make_float4(r1.w, r3.w, r5.w, r7.w);
}

// ---------------- fallback: generic planar atomics ----------------

__global__ __launch_bounds__(256) void deposit_tsc_gen(
    const float* __restrict__ pos,
    const float* __restrict__ cell,
    const float* __restrict__ emb,
    float* __restrict__ out,
    int N, int n, int C)
{
    int i = blockIdx.x * blockDim.x + threadIdx.x;
    if (i >= N) return;

    float inv_sp = inv_spacing(cell, n);

    float p[3], d[3];
    int c0[3];
    #pragma unroll
    for (int k = 0; k < 3; ++k) {
        p[k] = pos[3 * i + k] * inv_sp;
        c0[k] = (int)rintf(p[k]);
        d[k] = p[k] - (float)c0[k];
    }
    float w[3][3];
    #pragma unroll
    for (int k = 0; k < 3; ++k) {
        float dd = d[k], d2 = dd * dd;
        w[k][0] = 0.125f * (1.0f - 4.0f * dd + 4.0f * d2);
        w[k][1] = 0.25f  * (3.0f - 4.0f * d2);
        w[k][2] = 0.125f * (1.0f + 4.0f * dd + 4.0f * d2);
    }
    int W[3][3];
    #pragma unroll
    for (int k = 0; k < 3; ++k) {
        #pragma unroll
        for (int a = 0; a < 3; ++a) {
            int v = c0[k] - 1 + a; if (v < 0) v += n; else if (v >= n) v -= n;
            W[k][a] = v;
        }
    }
    int n3 = n * n * n;
    for (int a = 0; a < 3; ++a)
        for (int b = 0; b < 3; ++b)
            for (int cc = 0; cc < 3; ++cc) {
                float wt = w[0][a] * w[1][b] * w[2][cc];
                int g = (W[0][a] * n + W[1][b]) * n + W[2][cc];
                for (int ch = 0; ch < C; ++ch)
                    atomicAdd(out + (size_t)ch * n3 + g, wt * emb[(size_t)i * C + ch]);
            }
}

extern "C" void kernel_launch(void* const* d_in, const int* in_sizes, int n_in,
                              void* d_out, int out_size, void* d_ws, size_t ws_size,
                              hipStream_t stream) {
    const float* pos  = (const float*)d_in[0];
    const float* cell = (const float*)d_in[1];
    const float* emb  = (const float*)d_in[2];
    float* out = (float*)d_out;
    float* ws  = (float*)d_ws;

    int N = in_sizes[0] / 3;
    int C = in_sizes[2] / N;
    long long n3l = (long long)out_size / C;
    int n = (int)llroundf(cbrtf((float)n3l));
    int n3 = (int)n3l;

    int block = 256;

    // ---- wave-scatter fast path ----
    {
        int nb = n * n;
        size_t lds_bytes = (size_t)4 * 8 * n * sizeof(float);   // 128n B
        size_t rec_off = (((size_t)nb + 4 + (size_t)N) * sizeof(int) + 15) & ~(size_t)15;
        size_t need = rec_off + (size_t)nb * KColCAP * 48;
        bool ok = (C == 8) && (n % 4 == 0) && n >= 8 && n <= 256
                  && lds_bytes <= 64 * 1024
                  && ws_size >= need
                  && ((long long)n * n * n == n3l);
        if (ok) {
            int* counts  = (int*)d_ws;
            int* ovf_cnt = counts + nb;
            int* ovf     = counts + nb + 4;
            float4* binrec = (float4*)((char*)d_ws + rec_off);

            (void)hipMemsetAsync(counts, 0, (size_t)(nb + 4) * sizeof(int), stream);
            fill_recs<<<(N + block - 1) / block, block, 0, stream>>>(
                pos, cell, emb, counts, ovf_cnt, binrec, ovf, N, n);

            int nzc = n / 4;
            gather_scatter<<<nzc * n, block, lds_bytes, stream>>>(
                binrec, counts, out, n, nzc);

            deposit_overflow<<<(N + block - 1) / block, block, 0, stream>>>(
                pos, cell, emb, ovf_cnt, ovf, out, n);
            return;
        }
    }

    // ---- fallback: interleaved atomics + transpose ----
    size_t need = (size_t)out_size * sizeof(float);
    if (C == 8 && ws_size >= need && (n3 % 4) == 0) {
        (void)hipMemsetAsync(d_ws, 0, need, stream);
        int total = N * 27;
        deposit_tsc8_ilv<<<(total + block - 1) / block, block, 0, stream>>>(
            pos, cell, emb, ws, total, n);
        int tthreads = n3 / 4;
        transpose_ilv8<<<(tthreads + block - 1) / block, block, 0, stream>>>(
            ws, out, n3);
    } else {
        (void)hipMemsetAsync(d_out, 0, (size_t)out_size * sizeof(float), stream);
        int grid = (N + block - 1) / block;
        deposit_tsc_gen<<<grid, block, 0, stream>>>(pos, cell, emb, out, N, n, C);
    }
}

// Round 12
// 145.671 us; speedup vs baseline: 1.0060x; 1.0060x over previous
//
#include <hip/hip_runtime.h>
#include <hip/hip_fp16.h>
#include <math.h>

// TSC (order-3) particle-to-mesh deposition.
//
// Fast path (C==8, n%4==0, n<=256): per-1x1-column capped bin lists of
// PACKED 32B records (pos 3xf32 + emb 8xf16), then WAVE-SCATTER-GATHER:
// one wave per (x,y) column, lanes = (atom-slot, z-corner) pairs, 8
// ds_add_f32 into the wave's PRIVATE LDS column [8ch][n] (f32 accumulate),
// then per-channel float4 streaming writeout. r12 changes vs r11 (~146us):
//  (1) records 48B -> 32B (emb stored f16, accumulated f32): 2 loads per
//      record instead of 3; binrec 30->20 MB (better L2 residence);
//  (2) 2-deep software pipeline: round q+1's record loads are issued
//      before round q's deposit -- halves the per-wave serial global
//      round-trips that (post r11's null) we believe bound the kernel.
// Retained from r11: no block barrier (wave-private column), plain stores,
// bijective XCD swizzle.
//
// Fallbacks: interleaved-atomic two-phase (C==8), generic planar atomics.

#define KColCAP 16   // records per 1x1 column bin (lambda ~2.5)

typedef float nfloat4 __attribute__((ext_vector_type(4)));

// TSC weight for axis offset o in {-1,0,+1} at fractional distance d in [-0.5,0.5]
__device__ __forceinline__ float tsc_w(int o, float d) {
    float t = 0.5f + (float)o * d;
    return (o == 0) ? (0.75f - d * d) : (0.5f * t * t);
}

__device__ __forceinline__ float inv_spacing(const float* __restrict__ cell, int n) {
    float tr = cell[0] + cell[4] + cell[8];
    return (3.0f * (float)n) / tr;
}

__device__ __forceinline__ float2 unpack_h2(float bits) {
    unsigned int u = __float_as_uint(bits);
    __half2 h = *(__half2*)&u;
    return __half22float2(h);
}

// ---------------- binning: packed 32B records into 1x1-column lists ----------------

__global__ __launch_bounds__(256) void fill_recs(
    const float* __restrict__ pos, const float* __restrict__ cell,
    const float* __restrict__ emb,
    int* __restrict__ counts, int* __restrict__ ovf_cnt,
    float4* __restrict__ binrec, int* __restrict__ ovf,
    int N, int n)
{
    int i = blockIdx.x * blockDim.x + threadIdx.x;
    if (i >= N) return;
    float inv_sp = inv_spacing(cell, n);
    float px = pos[3 * i + 0] * inv_sp;
    float py = pos[3 * i + 1] * inv_sp;
    float pz = pos[3 * i + 2] * inv_sp;
    int cx = (int)rintf(px); if (cx >= n) cx -= n; else if (cx < 0) cx += n;
    int cy = (int)rintf(py); if (cy >= n) cy -= n; else if (cy < 0) cy += n;
    int bin = cx * n + cy;
    int slot = atomicAdd(&counts[bin], 1);
    if (slot < KColCAP) {
        const float4* e4 = (const float4*)(emb + (size_t)i * 8);
        float4 e0 = e4[0], e1 = e4[1];
        __half2 h01 = __floats2half2_rn(e0.x, e0.y);
        __half2 h23 = __floats2half2_rn(e0.z, e0.w);
        __half2 h45 = __floats2half2_rn(e1.x, e1.y);
        __half2 h67 = __floats2half2_rn(e1.z, e1.w);
        unsigned int u01 = *(unsigned int*)&h01;
        unsigned int u23 = *(unsigned int*)&h23;
        unsigned int u45 = *(unsigned int*)&h45;
        unsigned int u67 = *(unsigned int*)&h67;
        float4* r = binrec + (size_t)(bin * KColCAP + slot) * 2;
        r[0] = make_float4(px, py, pz, __uint_as_float(u01));
        r[1] = make_float4(__uint_as_float(u23), __uint_as_float(u45),
                           __uint_as_float(u67), 0.0f);
    } else {
        int o = atomicAdd(ovf_cnt, 1);
        ovf[o] = i;   // ovf sized N: cannot overflow
    }
}

// ---------------- wave-scatter gather: one wave per column ----------------
// 1D grid of nb = (n/4)*n blocks; bijective XCD swizzle maps block -> (x,ygrp).
// Wave wv handles column (x, ygrp*4+wv); LDS: per-wave private [8ch][n].

__global__ __launch_bounds__(256) void gather_scatter(
    const float4* __restrict__ binrec, const int* __restrict__ counts,
    float* __restrict__ out, int n, int nzc)
{
    extern __shared__ float lds[];
    const int tid = threadIdx.x;
    const int lane = tid & 63;
    const int wv = tid >> 6;

    // bijective XCD swizzle (m204)
    const int nb = nzc * n;
    const int b = blockIdx.x;
    const int q8 = nb >> 3, r8 = nb & 7;
    const int xcd = b & 7, idx = b >> 3;
    const int sb = (xcd < r8) ? (xcd * (q8 + 1) + idx)
                              : (r8 * (q8 + 1) + (xcd - r8) * q8 + idx);
    const int x = sb / nzc;
    const int ygrp = sb - x * nzc;
    const int y = ygrp * 4 + wv;

    float* col = lds + wv * 8 * n;     // [8][n] private to this wave

    // zero this wave's column (8n floats = 2n float4)
    {
        nfloat4* c4 = (nfloat4*)col;
        const int z4 = 2 * n;
        for (int i = lane; i < z4; i += 64)
            c4[i] = (nfloat4)(0.f);
    }

    // 9 neighbor-bin meta in registers (wave-uniform broadcast loads)
    int base[9], pref[10];
    pref[0] = 0;
    #pragma unroll
    for (int j = 0; j < 9; ++j) {
        int jx = j / 3, jy = j - 3 * (j / 3);       // compile-time per j
        int xb = x + jx - 1; if (xb < 0) xb += n; else if (xb >= n) xb -= n;
        int yb = y + jy - 1; if (yb < 0) yb += n; else if (yb >= n) yb -= n;
        int bin = xb * n + yb;
        base[j] = bin * KColCAP;
        int c = counts[bin];
        c = (c < KColCAP) ? c : KColCAP;
        pref[j + 1] = pref[j] + c;
    }
    const int tot = pref[9];

    // lane = (atom slot s, z-corner zc)
    const int s  = lane / 3;           // 0..21 (lane 63 -> s=21, inactive)
    const int zc = lane - 3 * s - 1;   // -1, 0, +1

    // 2-deep pipelined rounds: fetch round q+1 before depositing round q.
    float4 a0, a1; int jxA = 0, jyA = 0;
    bool vA = (s < 21) && (s < tot);
    if (vA) {
        int rec = base[0] + s; int jxv = 0, jyv = 0;
        #pragma unroll
        for (int k = 1; k < 9; ++k) {
            bool ge = (s >= pref[k]);
            int cand = base[k] + (s - pref[k]);
            rec = ge ? cand : rec;
            jxv = ge ? (k / 3) : jxv;
            jyv = ge ? (k - 3 * (k / 3)) : jyv;
        }
        a0 = binrec[2 * (size_t)rec];
        a1 = binrec[2 * (size_t)rec + 1];
        jxA = jxv; jyA = jyv;
    }

    for (int q0 = 0; q0 < tot; q0 += 21) {
        // prefetch next round's record
        const int qn = q0 + 21 + s;
        const bool vB = (s < 21) && (qn < tot);
        float4 b0 = a0, b1 = a1; int jxB = jxA, jyB = jyA;
        if (vB) {
            int rec = base[0] + qn; int jxv = 0, jyv = 0;
            #pragma unroll
            for (int k = 1; k < 9; ++k) {
                bool ge = (qn >= pref[k]);
                int cand = base[k] + (qn - pref[k]);
                rec = ge ? cand : rec;
                jxv = ge ? (k / 3) : jxv;
                jyv = ge ? (k - 3 * (k / 3)) : jyv;
            }
            b0 = binrec[2 * (size_t)rec];
            b1 = binrec[2 * (size_t)rec + 1];
            jxB = jxv; jyB = jyv;
        }

        // deposit current round
        if (vA) {
            float cxf = rintf(a0.x); float dx = a0.x - cxf;
            float cyf = rintf(a0.y); float dy = a0.y - cyf;
            float czf = rintf(a0.z); float dz = a0.z - czf;

            float tx = 0.5f + (float)(1 - jxA) * dx;
            float wx = (jxA == 1) ? (0.75f - dx * dx) : (0.5f * tx * tx);
            float ty = 0.5f + (float)(1 - jyA) * dy;
            float wy = (jyA == 1) ? (0.75f - dy * dy) : (0.5f * ty * ty);
            float tz = 0.5f + (float)zc * dz;
            float wz = (zc == 0) ? (0.75f - dz * dz) : (0.5f * tz * tz);
            float w = wx * wy * wz;

            float2 e01 = unpack_h2(a0.w);
            float2 e23 = unpack_h2(a1.x);
            float2 e45 = unpack_h2(a1.y);
            float2 e67 = unpack_h2(a1.z);

            int cz = (int)czf; if (cz >= n) cz -= n; else if (cz < 0) cz += n;
            int z = cz + zc; if (z < 0) z += n; else if (z >= n) z -= n;

            float* p = col + z;                       // ch stride n
            atomicAdd(p + 0 * n, w * e01.x);
            atomicAdd(p + 1 * n, w * e01.y);
            atomicAdd(p + 2 * n, w * e23.x);
            atomicAdd(p + 3 * n, w * e23.y);
            atomicAdd(p + 4 * n, w * e45.x);
            atomicAdd(p + 5 * n, w * e45.y);
            atomicAdd(p + 6 * n, w * e67.x);
            atomicAdd(p + 7 * n, w * e67.y);
        }
        a0 = b0; a1 = b1; jxA = jxB; jyA = jyB; vA = vB;
    }
    // No __syncthreads(): column is wave-private; DS ops are in-order per wave.

    // writeout: per channel one PLAIN float4 per lane (z = 4*lane..+3)
    const int z0 = lane * 4;
    if (z0 < n) {
        const size_t n3 = (size_t)n * n * n;
        const size_t colbase = ((size_t)x * n + y) * (size_t)n + z0;
        #pragma unroll
        for (int ch = 0; ch < 8; ++ch) {
            nfloat4 v = *(const nfloat4*)(col + ch * n + z0);
            *(nfloat4*)(out + (size_t)ch * n3 + colbase) = v;
        }
    }
}

// overflow cleanup: global planar atomics for atoms that missed their bin list
__global__ __launch_bounds__(256) void deposit_overflow(
    const float* __restrict__ pos, const float* __restrict__ cell,
    const float* __restrict__ emb, const int* __restrict__ ovf_cnt,
    const int* __restrict__ ovf, float* __restrict__ out, int n)
{
    int m = *ovf_cnt;
    int i = blockIdx.x * blockDim.x + threadIdx.x;
    if (i >= m) return;
    int ai = ovf[i];
    float inv_sp = inv_spacing(cell, n);
    float p[3], d[3]; int c0[3];
    #pragma unroll
    for (int kk = 0; kk < 3; ++kk) {
        p[kk] = pos[3 * ai + kk] * inv_sp;
        c0[kk] = (int)rintf(p[kk]);
        d[kk] = p[kk] - (float)c0[kk];
    }
    float w[3][3];
    #pragma unroll
    for (int kk = 0; kk < 3; ++kk) {
        float dd = d[kk];
        w[kk][0] = tsc_w(-1, dd); w[kk][1] = tsc_w(0, dd); w[kk][2] = tsc_w(1, dd);
    }
    int W[3][3];
    #pragma unroll
    for (int kk = 0; kk < 3; ++kk)
        #pragma unroll
        for (int a = 0; a < 3; ++a) {
            int v = c0[kk] - 1 + a; if (v < 0) v += n; else if (v >= n) v -= n;
            W[kk][a] = v;
        }
    size_t n3 = (size_t)n * n * n;
    const float4* e4 = (const float4*)(emb + (size_t)ai * 8);
    float4 e0 = e4[0], e1 = e4[1];
    float e[8] = {e0.x, e0.y, e0.z, e0.w, e1.x, e1.y, e1.z, e1.w};
    for (int a = 0; a < 3; ++a)
        for (int bq = 0; bq < 3; ++bq)
            for (int cq = 0; cq < 3; ++cq) {
                float wt = w[0][a] * w[1][bq] * w[2][cq];
                size_t g = ((size_t)W[0][a] * n + W[1][bq]) * n + W[2][cq];
                #pragma unroll
                for (int ch = 0; ch < 8; ++ch)
                    atomicAdd(out + (size_t)ch * n3 + g, wt * e[ch]);
            }
}

// ---------------- fallback: interleaved atomics + transpose ----------------

__global__ __launch_bounds__(256) void deposit_tsc8_ilv(
    const float* __restrict__ pos,
    const float* __restrict__ cell,
    const float* __restrict__ emb,
    float* __restrict__ ws,
    int total, int n)
{
    int t = blockIdx.x * blockDim.x + threadIdx.x;
    if (t >= total) return;
    int atom = t / 27;
    int c    = t - atom * 27;
    int a    = c / 9;
    int rem  = c - a * 9;
    int b    = rem / 3;
    int cc   = rem - b * 3;

    float inv_sp = inv_spacing(cell, n);

    float px = pos[3 * atom + 0] * inv_sp;
    float py = pos[3 * atom + 1] * inv_sp;
    float pz = pos[3 * atom + 2] * inv_sp;

    int cx = (int)rintf(px);  float dx = px - (float)cx;
    int cy = (int)rintf(py);  float dy = py - (float)cy;
    int cz = (int)rintf(pz);  float dz = pz - (float)cz;

    float w = tsc_w(a - 1, dx) * tsc_w(b - 1, dy) * tsc_w(cc - 1, dz);

    int x = cx - 1 + a;  if (x < 0) x += n; else if (x >= n) x -= n;
    int y = cy - 1 + b;  if (y < 0) y += n; else if (y >= n) y -= n;
    int z = cz - 1 + cc; if (z < 0) z += n; else if (z >= n) z -= n;

    const float4* e4 = (const float4*)(emb + (size_t)atom * 8);
    float4 e0 = e4[0], e1 = e4[1];

    float* p = ws + ((size_t)((x * n + y) * n + z)) * 8;
    atomicAdd(p + 0, w * e0.x);
    atomicAdd(p + 1, w * e0.y);
    atomicAdd(p + 2, w * e0.z);
    atomicAdd(p + 3, w * e0.w);
    atomicAdd(p + 4, w * e1.x);
    atomicAdd(p + 5, w * e1.y);
    atomicAdd(p + 6, w * e1.z);
    atomicAdd(p + 7, w * e1.w);
}

__global__ __launch_bounds__(256) void transpose_ilv8(
    const float* __restrict__ ws, float* __restrict__ out, int n3)
{
    int t = blockIdx.x * blockDim.x + threadIdx.x;
    int g0 = t * 4;
    if (g0 >= n3) return;
    const float4* w4 = (const float4*)(ws + (size_t)g0 * 8);
    float4 r0 = w4[0], r1 = w4[1];
    float4 r2 = w4[2], r3 = w4[3];
    float4 r4 = w4[4], r5 = w4[5];
    float4 r6 = w4[6], r7 = w4[7];

    *(float4*)(out + (size_t)0 * n3 + g0) = make_float4(r0.x, r2.x, r4.x, r6.x);
    *(float4*)(out + (size_t)1 * n3 + g0) = make_float4(r0.y, r2.y, r4.y, r6.y);
    *(float4*)(out + (size_t)2 * n3 + g0) = make_float4(r0.z, r2.z, r4.z, r6.z);
    *(float4*)(out + (size_t)3 * n3 + g0) = make_float4(r0.w, r2.w, r4.w, r6.w);
    *(float4*)(out + (size_t)4 * n3 + g0) = make_float4(r1.x, r3.x, r5.x, r7.x);
    *(float4*)(out + (size_t)5 * n3 + g0) = make_float4(r1.y, r3.y, r5.y, r7.y);
    *(float4*)(out + (size_t)6 * n3 + g0) = make_float4(r1.z, r3.z, r5.z, r7.z);
    *(float4*)(out + (size_t)7 * n3 + g0) = make_float4(r1.w, r3.w, r5.w, r7.w);
}

// ---------------- fallback: generic planar atomics ----------------

__global__ __launch_bounds__(256) void deposit_tsc_gen(
    const float* __restrict__ pos,
    const float* __restrict__ cell,
    const float* __restrict__ emb,
    float* __restrict__ out,
    int N, int n, int C)
{
    int i = blockIdx.x * blockDim.x + threadIdx.x;
    if (i >= N) return;

    float inv_sp = inv_spacing(cell, n);

    float p[3], d[3];
    int c0[3];
    #pragma unroll
    for (int k = 0; k < 3; ++k) {
        p[k] = pos[3 * i + k] * inv_sp;
        c0[k] = (int)rintf(p[k]);
        d[k] = p[k] - (float)c0[k];
    }
    float w[3][3];
    #pragma unroll
    for (int k = 0; k < 3; ++k) {
        float dd = d[k], d2 = dd * dd;
        w[k][0] = 0.125f * (1.0f - 4.0f * dd + 4.0f * d2);
        w[k][1] = 0.25f  * (3.0f - 4.0f * d2);
        w[k][2] = 0.125f * (1.0f + 4.0f * dd + 4.0f * d2);
    }
    int W[3][3];
    #pragma unroll
    for (int k = 0; k < 3; ++k) {
        #pragma unroll
        for (int a = 0; a < 3; ++a) {
            int v = c0[k] - 1 + a; if (v < 0) v += n; else if (v >= n) v -= n;
            W[k][a] = v;
        }
    }
    int n3 = n * n * n;
    for (int a = 0; a < 3; ++a)
        for (int b = 0; b < 3; ++b)
            for (int cc = 0; cc < 3; ++cc) {
                float wt = w[0][a] * w[1][b] * w[2][cc];
                int g = (W[0][a] * n + W[1][b]) * n + W[2][cc];
                for (int ch = 0; ch < C; ++ch)
                    atomicAdd(out + (size_t)ch * n3 + g, wt * emb[(size_t)i * C + ch]);
            }
}

extern "C" void kernel_launch(void* const* d_in, const int* in_sizes, int n_in,
                              void* d_out, int out_size, void* d_ws, size_t ws_size,
                              hipStream_t stream) {
    const float* pos  = (const float*)d_in[0];
    const float* cell = (const float*)d_in[1];
    const float* emb  = (const float*)d_in[2];
    float* out = (float*)d_out;
    float* ws  = (float*)d_ws;

    int N = in_sizes[0] / 3;
    int C = in_sizes[2] / N;
    long long n3l = (long long)out_size / C;
    int n = (int)llroundf(cbrtf((float)n3l));
    int n3 = (int)n3l;

    int block = 256;

    // ---- wave-scatter fast path ----
    {
        int nb = n * n;
        size_t lds_bytes = (size_t)4 * 8 * n * sizeof(float);   // 128n B
        size_t rec_off = (((size_t)nb + 4 + (size_t)N) * sizeof(int) + 15) & ~(size_t)15;
        size_t need = rec_off + (size_t)nb * KColCAP * 32;
        bool ok = (C == 8) && (n % 4 == 0) && n >= 8 && n <= 256
                  && lds_bytes <= 64 * 1024
                  && ws_size >= need
                  && ((long long)n * n * n == n3l);
        if (ok) {
            int* counts  = (int*)d_ws;
            int* ovf_cnt = counts + nb;
            int* ovf     = counts + nb + 4;
            float4* binrec = (float4*)((char*)d_ws + rec_off);

            (void)hipMemsetAsync(counts, 0, (size_t)(nb + 4) * sizeof(int), stream);
            fill_recs<<<(N + block - 1) / block, block, 0, stream>>>(
                pos, cell, emb, counts, ovf_cnt, binrec, ovf, N, n);

            int nzc = n / 4;
            gather_scatter<<<nzc * n, block, lds_bytes, stream>>>(
                binrec, counts, out, n, nzc);

            deposit_overflow<<<(N + block - 1) / block, block, 0, stream>>>(
                pos, cell, emb, ovf_cnt, ovf, out, n);
            return;
        }
    }

    // ---- fallback: interleaved atomics + transpose ----
    size_t need = (size_t)out_size * sizeof(float);
    if (C == 8 && ws_size >= need && (n3 % 4) == 0) {
        (void)hipMemsetAsync(d_ws, 0, need, stream);
        int total = N * 27;
        deposit_tsc8_ilv<<<(total + block - 1) / block, block, 0, stream>>>(
            pos, cell, emb, ws, total, n);
        int tthreads = n3 / 4;
        transpose_ilv8<<<(tthreads + block - 1) / block, block, 0, stream>>>(
            ws, out, n3);
    } else {
        (void)hipMemsetAsync(d_out, 0, (size_t)out_size * sizeof(float), stream);
        int grid = (N + block - 1) / block;
        deposit_tsc_gen<<<grid, block, 0, stream>>>(pos, cell, emb, out, N, n, C);
    }
}